// Round 5
// baseline (508.903 us; speedup 1.0000x reference)
//
#include <hip/hip_runtime.h>
#include <hip/hip_bf16.h>
#include <stdint.h>

// Problem constants (QuantizedLinear_22849226015470)
#define MROWS 8192      // 4*2048 activation rows
#define K_TOT 4096      // in_features
#define N_TOT 4096      // out_features
// trellis: NB=65536 tiles (256 out-tiles x 256 in-tiles of 16x16), 32 x 16-bit
// words per tile; state_t = 16-bit big-endian window at bit 2t (circular 512).
//
// Identity used here: out = (x·(I⊗H))·Wˢᵀ = x·(Wˢ·(I⊗H))ᵀ  (H128 symmetric),
// and the per-(row,128-group) scale commutes with H within its group. So we
// rotate the decoded WEIGHTS via MFMA (H entries ±1, exact in bf16; 1/√128
// folded into the scale) and the activation path is a pure fp32→bf16 convert.

typedef __attribute__((ext_vector_type(8))) short bf16x8;
typedef __attribute__((ext_vector_type(4))) float f32x4;
typedef __attribute__((ext_vector_type(8))) unsigned short ushort8;
typedef __attribute__((ext_vector_type(4))) unsigned short ushort4v;

#define GLB(p) ((const __attribute__((address_space(1))) void*)(p))
#define LDSP(p) ((__attribute__((address_space(3))) void*)(p))

// ---------------- activation convert: fp32 -> bf16 (pure BW) ----------------
// grid-stride (G11): 2048 blocks x 256 thr x 8 elems x 8 iters = 33.55M elems
__global__ __launch_bounds__(256) void conv_k(const float* __restrict__ in,
                                              __hip_bfloat16* __restrict__ xb) {
    const long stride = (long)2048 * 256 * 8;
    long base = ((long)blockIdx.x * 256 + threadIdx.x) * 8;
#pragma unroll
    for (int it = 0; it < 8; ++it, base += stride) {
        float4 x0 = *(const float4*)(in + base);
        float4 x1 = *(const float4*)(in + base + 4);
        ushort8 u;
        __hip_bfloat16 h;
        h = __float2bfloat16(x0.x); u[0] = *(unsigned short*)&h;
        h = __float2bfloat16(x0.y); u[1] = *(unsigned short*)&h;
        h = __float2bfloat16(x0.z); u[2] = *(unsigned short*)&h;
        h = __float2bfloat16(x0.w); u[3] = *(unsigned short*)&h;
        h = __float2bfloat16(x1.x); u[4] = *(unsigned short*)&h;
        h = __float2bfloat16(x1.y); u[5] = *(unsigned short*)&h;
        h = __float2bfloat16(x1.z); u[6] = *(unsigned short*)&h;
        h = __float2bfloat16(x1.w); u[7] = *(unsigned short*)&h;
        *(ushort8*)((unsigned short*)xb + base) = u;
    }
}

// ---------------- trellis decode + H128 rotate ------------------------------
// v3: 256 blocks x 1024 threads (16 waves = 4/SIMD for latency hiding).
// Block = one out-row tile (tbx): LUT staged ONCE per block (was: per 8
// strips), trellis words staged in two 16KB passes of 16 strips each.
// LDS = 128K (bf16 LUT) + 16K (128 tiles x 32 words) = 144 KB, 1 block/CU.
// Per-element math bit-identical to v2 (bf16(tlut[st]) LUT, in-register H).
__global__ __launch_bounds__(1024) void dec_k(const int* __restrict__ trellis,
                                              const float* __restrict__ tlut,
                                              const float* __restrict__ scales,
                                              __hip_bfloat16* __restrict__ wb) {
    __shared__ unsigned short tl[65536];           // bf16 LUT, 128 KB
    __shared__ uint32_t sw[4096];                  // 128 tiles x 32 words, 16 KB
    const int tid = threadIdx.x;
    const int tbx = blockIdx.x;        // out-row tile (0..255)

    // ---- stage LUT once: coalesced float4 reads, pack to bf16 ----
#pragma unroll
    for (int it = 0; it < 16; ++it) {
        const int idx = it * 4096 + tid * 4;
        float4 f = *(const float4*)(tlut + idx);
        ushort4v u;
        __hip_bfloat16 h;
        h = __float2bfloat16(f.x); u[0] = *(unsigned short*)&h;
        h = __float2bfloat16(f.y); u[1] = *(unsigned short*)&h;
        h = __float2bfloat16(f.z); u[2] = *(unsigned short*)&h;
        h = __float2bfloat16(f.w); u[3] = *(unsigned short*)&h;
        *(ushort4v*)&tl[idx] = u;
    }

    const int wave = tid >> 6;         // 0..15
    const int lane = tid & 63;
    const int m = lane & 15;           // out-row within strip
    const int quad = lane >> 4;

    for (int pass = 0; pass < 2; ++pass) {
        // ---- stage 128 tiles' words (groups pass*16 .. pass*16+15) ----
        __syncthreads();   // pass 1: all pass-0 sw reads done before overwrite
        {
            int4 v = *((const int4*)(trellis + ((long)tbx * 256 + pass * 128) * 32) + tid);
            sw[tid * 4 + 0] = (uint32_t)v.x & 0xFFFFu;
            sw[tid * 4 + 1] = (uint32_t)v.y & 0xFFFFu;
            sw[tid * 4 + 2] = (uint32_t)v.z & 0xFFFFu;
            sw[tid * 4 + 3] = (uint32_t)v.w & 0xFFFFu;
        }
        __syncthreads();

        const int g = pass * 16 + wave;            // 128-group index (0..31)

        // decode A-fragments: af[kc] holds Wdec[m][kc*32 + quad*8 + j]
        bf16x8 af[4];
#pragma unroll
        for (int kc = 0; kc < 4; kc++) {
#pragma unroll
            for (int j = 0; j < 8; j++) {
                const int k = kc * 32 + quad * 8 + j;   // col within strip
                const int tile = wave * 8 + (k >> 4);   // tile in LDS
                const int c = k & 15;                   // col within tile
                const int t = m * 16 + c;               // state index
                const int q = t >> 3;                   // word index
                const int rb = (c & 7) * 2;             // bit offset (even)
                const uint32_t w0 = sw[tile * 32 + q];
                const uint32_t w1 = sw[tile * 32 + ((q + 1) & 31)];
                const uint32_t st = ((w0 << rb) | (w1 >> (16 - rb))) & 0xFFFFu;
                af[kc][j] = (short)tl[st];              // bf16 LUT hit in LDS
            }
        }
        // per-lane output-row scales (row = quad*4 + reg), 1/sqrt(128) folded
        float scl[4];
#pragma unroll
        for (int r = 0; r < 4; r++)
            scl[r] = scales[(tbx * 16 + quad * 4 + r) * 32 + g] * 0.088388347648318447f;

        // rotate: for each 16-col output tile, C = Wdec(16x128) · H-frags
#pragma unroll
        for (int nt = 0; nt < 8; nt++) {
            f32x4 c = {};
            const int n = nt * 16 + m;
#pragma unroll
            for (int kc = 0; kc < 4; kc++) {
                bf16x8 bf;
#pragma unroll
                for (int j = 0; j < 8; j++) {
                    const int k = kc * 32 + quad * 8 + j;
                    bf[j] = (short)((__popc(n & k) & 1) ? 0xBF80 : 0x3F80);
                }
                c = __builtin_amdgcn_mfma_f32_16x16x32_bf16(af[kc], bf, c, 0, 0, 0);
            }
            const long col = (long)g * 128 + nt * 16 + m;   // C/D: col = lane&15
#pragma unroll
            for (int r = 0; r < 4; r++) {
                const long orow = tbx * 16 + quad * 4 + r;  // C/D: row = quad*4+reg
                wb[orow * K_TOT + col] = __float2bfloat16(c[r] * scl[r]);
            }
        }
    }
}

// ---------------- bf16 GEMM: C[m,n] = sum_k A[m,k]*B[n,k]  (both K-contig) --
// 256x256 tile, BK=32, 512 threads (8 waves, 2M x 4N), depth-3 counted-vmcnt
// pipeline over 4 LDS buffers (128 KiB): iteration t issues tile t+3's
// global_load_lds, computes tile t, waits s_waitcnt vmcnt(8) (never 0) at the
// single raw s_barrier per iteration. WAR: slot (t+3)&3 == (t-1)&3, last read
// in iter t-1 whose end barrier we've passed. RAW: 12 outstanding - wait 8
// retires the 4 oldest = tile t+1 (in-order vmcnt retirement).
// [round-1 depth-2 verified 248us/0-conflict/Mfma 50; 2-phase split regressed]
// LDS granule swizzle (T2, 64B rows): logical (row, kseg) at physical
// kseg ^ ((row>>1)&3), applied on GLOBAL source addr (LDS writes stay linear
// as global_load_lds requires) and on the ds_read addr -> 0 bank conflicts.
#define BK 32
#define NTILES (K_TOT / BK)       // 128
#define BUFSZ 32768               // A 16KB + B 16KB per K-tile

__global__ __launch_bounds__(512, 2) void gemm_k(const __hip_bfloat16* __restrict__ A,
                                                 const __hip_bfloat16* __restrict__ B,
                                                 float* __restrict__ C) {
    __shared__ __align__(16) char sbuf[4 * BUFSZ];   // 128 KiB
    const int tid  = threadIdx.x;
    const int wave = tid >> 6;
    const int lane = tid & 63;
    const long m0 = (long)blockIdx.y * 256;
    const long n0 = (long)blockIdx.x * 256;

    // wave grid: 2 (M) x 4 (N); wave owns 128x64 of C
    const int wm = wave >> 2;          // 0..1
    const int wn = wave & 3;           // 0..3

    // ---- staging source pointers (per-thread, pre-swizzled global addr) ----
    const __hip_bfloat16* srcA[2];
    const __hip_bfloat16* srcB[2];
#pragma unroll
    for (int j = 0; j < 2; j++) {
        const int p   = j * 512 + tid;
        const int row = p >> 2;
        const int seg = (p & 3) ^ ((row >> 1) & 3);
        srcA[j] = A + (m0 + row) * K_TOT + seg * 8;
        srcB[j] = B + (n0 + row) * K_TOT + seg * 8;
    }
    const int ldsOff0 = wave * 1024;
    const int ldsOff1 = 8192 + wave * 1024;

    // ---- ds_read addressing (swizzled) ----
    const int lr  = lane & 15;
    const int lq  = lane >> 4;
    const int xsw = (lq ^ ((lr >> 1) & 3)) * 16;   // swizzled 16B granule off
    const int arow0 = wm * 128 + lr;               // + i*16
    const int brow0 = wn * 64 + lr;                // + j*16

    f32x4 acc[8][4] = {};

#define STAGE(tt)                                                                         \
    do {                                                                                  \
        char* _b = (char*)sbuf + ((tt) & 3) * BUFSZ;                                      \
        const long _ko = (long)(tt) * BK;                                                 \
        __builtin_amdgcn_global_load_lds(GLB(srcA[0] + _ko), LDSP(_b + ldsOff0), 16, 0, 0);\
        __builtin_amdgcn_global_load_lds(GLB(srcA[1] + _ko), LDSP(_b + ldsOff1), 16, 0, 0);\
        __builtin_amdgcn_global_load_lds(GLB(srcB[0] + _ko), LDSP(_b + 16384 + ldsOff0), 16, 0, 0);\
        __builtin_amdgcn_global_load_lds(GLB(srcB[1] + _ko), LDSP(_b + 16384 + ldsOff1), 16, 0, 0);\
    } while (0)

    // prologue: tiles 0,1,2 issued; wait tile 0 landed (8 stay in flight)
    STAGE(0);
    STAGE(1);
    STAGE(2);
    asm volatile("s_waitcnt vmcnt(8)" ::: "memory");
    __builtin_amdgcn_s_barrier();
    asm volatile("" ::: "memory");

    for (int t = 0; t < NTILES; ++t) {
        if (t + 3 < NTILES) STAGE(t + 3);

        const char* bufA = (const char*)sbuf + (t & 3) * BUFSZ;
        const char* bufB = bufA + 16384;

        bf16x8 bfr[4], af[4];
#pragma unroll
        for (int j = 0; j < 4; j++)
            bfr[j] = *(const bf16x8*)(bufB + (brow0 + j * 16) * 64 + xsw);
#pragma unroll
        for (int i = 0; i < 4; i++)
            af[i] = *(const bf16x8*)(bufA + (arow0 + i * 16) * 64 + xsw);

        __builtin_amdgcn_s_setprio(1);
#pragma unroll
        for (int i = 0; i < 4; i++)
#pragma unroll
            for (int j = 0; j < 4; j++)
                acc[i][j] = __builtin_amdgcn_mfma_f32_16x16x32_bf16(af[i], bfr[j], acc[i][j], 0, 0, 0);
        __builtin_amdgcn_s_setprio(0);

#pragma unroll
        for (int i = 0; i < 4; i++)
            af[i] = *(const bf16x8*)(bufA + (arow0 + (i + 4) * 16) * 64 + xsw);

        __builtin_amdgcn_s_setprio(1);
#pragma unroll
        for (int i = 0; i < 4; i++)
#pragma unroll
            for (int j = 0; j < 4; j++)
                acc[i + 4][j] = __builtin_amdgcn_mfma_f32_16x16x32_bf16(af[i], bfr[j], acc[i + 4][j], 0, 0, 0);
        __builtin_amdgcn_s_setprio(0);

        // counted wait: ensure tile t+1 fully landed before its barrier
        if (t + 3 < NTILES)      asm volatile("s_waitcnt vmcnt(8)" ::: "memory");
        else if (t + 2 < NTILES) asm volatile("s_waitcnt vmcnt(4)" ::: "memory");
        else if (t + 1 < NTILES) asm volatile("s_waitcnt vmcnt(0)" ::: "memory");
        if (t + 1 < NTILES) {
            __builtin_amdgcn_s_barrier();
            asm volatile("" ::: "memory");
        }
    }
#undef STAGE

    // epilogue: C/D layout col = lane&15, row = lq*4 + r
#pragma unroll
    for (int i = 0; i < 8; i++)
#pragma unroll
        for (int j = 0; j < 4; j++) {
            const long m = m0 + wm * 128 + i * 16 + lq * 4;
            const long n = n0 + wn * 64 + j * 16 + lr;
            float* cp = C + m * N_TOT + n;
#pragma unroll
            for (int r = 0; r < 4; r++)
                cp[(long)r * N_TOT] = acc[i][j][r];
        }
}

extern "C" void kernel_launch(void* const* d_in, const int* in_sizes, int n_in,
                              void* d_out, int out_size, void* d_ws, size_t ws_size,
                              hipStream_t stream) {
    const float* inp     = (const float*)d_in[0];   // (4,2048,4096) fp32
    const int*   trellis = (const int*)d_in[1];     // (65536,32) int32 (16-bit words)
    const float* tlut    = (const float*)d_in[2];   // (65536,1) fp32
    const float* scales  = (const float*)d_in[3];   // (131072,1) fp32
    float* out = (float*)d_out;                     // (4,2048,4096) fp32

    __hip_bfloat16* xb = (__hip_bfloat16*)d_ws;               // 64 MB
    __hip_bfloat16* wb = xb + (size_t)MROWS * K_TOT;          // 32 MB

    hipLaunchKernelGGL(conv_k, dim3(2048), dim3(256), 0, stream, inp, xb);
    hipLaunchKernelGGL(dec_k, dim3(256), dim3(1024), 0, stream, trellis, tlut, scales, wb);
    hipLaunchKernelGGL(gemm_k, dim3(N_TOT / 256, MROWS / 256), dim3(512), 0, stream, xb, wb, out);
}